// Round 1
// baseline (655.258 us; speedup 1.0000x reference)
//
#include <hip/hip_runtime.h>
#include <hip/hip_bf16.h>

#define BB 8
#define CC 256
#define HH 128
#define WW 128
#define KS 9
#define PADR 4
#define NPIX (BB*HH*WW)   // 131072
#define KDIM (4*CC)       // 1024

typedef __attribute__((ext_vector_type(8))) short bf16x8;
typedef __attribute__((ext_vector_type(4))) float f32x4;

static __device__ __forceinline__ unsigned short f2bf(float f) {
  union { float f; unsigned u; } v; v.f = f;
  unsigned r = v.u + 0x7FFF + ((v.u >> 16) & 1);   // RNE
  return (unsigned short)(r >> 16);
}

// ---------------------------------------------------------------------------
// Prep: A'[o][k'] bf16, k' = c*4 + t, from wproj[o][t*256 + c] (fp32)
// ---------------------------------------------------------------------------
__global__ void prep_kernel(const float* __restrict__ wproj,
                            unsigned short* __restrict__ Ap) {
  int idx = blockIdx.x * 256 + threadIdx.x;    // 0 .. 262143
  int o  = idx >> 10;
  int kp = idx & 1023;
  int c  = kp >> 2;
  int t  = kp & 3;
  Ap[idx] = f2bf(wproj[o * 1024 + t * 256 + c]);
}

// ---------------------------------------------------------------------------
// K1: depthwise convs -> Y bf16, Y[p][k'] with p = (b*H + h)*W + w, k' = c*4+t
// One thread: fixed (b,c,h), 8 consecutive w, all 4 conv types.
// Register sliding windows, no LDS. Block = 256 thr = 16 h x 16 w-groups.
// ---------------------------------------------------------------------------
__global__ __launch_bounds__(256)
void conv_kernel(const float* __restrict__ x,
                 const float* __restrict__ wh1, const float* __restrict__ wh2,
                 const float* __restrict__ wv1, const float* __restrict__ wv2,
                 unsigned short* __restrict__ Y) {
  int bid = blockIdx.x;           // ((b*C + c)*8 + ht)
  int ht  = bid & 7;
  int bc  = bid >> 3;             // b*C + c
  int c   = bc & 255;
  int tid = threadIdx.x;
  int hh  = tid >> 4;             // 0..15
  int w0  = (tid & 15) * 8;       // 0..120
  int h   = ht * 16 + hh;

  // weights: c is block-uniform -> scalar loads
  float swh1[KS], swh2[KS], swv1[KS], swv2[KS];
#pragma unroll
  for (int k = 0; k < KS; ++k) {
    swh1[k] = wh1[c * KS + k];
    swh2[k] = wh2[c * KS + k];
    swv1[k] = wv1[c * KS + k];
    swv2[k] = wv2[c * KS + k];
  }

  const float* xc = x + (size_t)bc * (HH * WW);

  // horizontal window [w0-4, w0+12)
  float hw[16];
  {
    const float* xrow = xc + h * WW;
#pragma unroll
    for (int s = 0; s < 4; ++s) {
      int wb = w0 - 4 + s * 4;
      float4 seg;
      if (wb >= 0 && wb <= WW - 4) seg = *(const float4*)(xrow + wb);
      else seg = make_float4(0.f, 0.f, 0.f, 0.f);
      hw[s*4+0] = seg.x; hw[s*4+1] = seg.y; hw[s*4+2] = seg.z; hw[s*4+3] = seg.w;
    }
  }

  // vertical windows: rows h-4..h+4, cols [w0, w0+8)
  float vv[KS][8];
#pragma unroll
  for (int k = 0; k < KS; ++k) {
    int r = h + k - PADR;
    if (r >= 0 && r < HH) {
      const float* rp = xc + r * WW + w0;
      float4 a = *(const float4*)(rp);
      float4 b4 = *(const float4*)(rp + 4);
      vv[k][0]=a.x; vv[k][1]=a.y; vv[k][2]=a.z; vv[k][3]=a.w;
      vv[k][4]=b4.x; vv[k][5]=b4.y; vv[k][6]=b4.z; vv[k][7]=b4.w;
    } else {
#pragma unroll
      for (int j = 0; j < 8; ++j) vv[k][j] = 0.f;
    }
  }

  int b = bc >> 8;
  size_t ybase = ((size_t)((b * HH + h) * WW + w0)) * KDIM + (size_t)c * 4;

#pragma unroll
  for (int w = 0; w < 8; ++w) {
    float s1 = 0.f, s2 = 0.f, s3 = 0.f, s4 = 0.f;
#pragma unroll
    for (int k = 0; k < KS; ++k) {
      float xh = hw[w + k];
      s1 = fmaf(xh, swh1[k], s1);
      s2 = fmaf(xh, swh2[k], s2);
      float xv = vv[k][w];
      s3 = fmaf(xv, swv1[k], s3);
      s4 = fmaf(xv, swv2[k], s4);
    }
    unsigned u0 = (unsigned)f2bf(s1) | ((unsigned)f2bf(s2) << 16);
    unsigned u1 = (unsigned)f2bf(s3) | ((unsigned)f2bf(s4) << 16);
    *(uint2*)(Y + ybase + (size_t)w * KDIM) = make_uint2(u0, u1);
  }
}

// ---------------------------------------------------------------------------
// K2: out(256 x 131072) = relu(A'(256x1024) @ Y^T), bf16 MFMA 16x16x32.
// Block = one pixel row (b,h): BM=256, BN=128, 512 thr = 8 waves (4M x 2N),
// wave tile 64o x 64p, register-direct loads (no LDS).
// ---------------------------------------------------------------------------
__global__ __launch_bounds__(512)
void gemm_kernel(const unsigned short* __restrict__ Ap,
                 const unsigned short* __restrict__ Yg,
                 float* __restrict__ out) {
  int bid  = blockIdx.x;          // 0..1023 = b*H + h
  int tid  = threadIdx.x;
  int lane = tid & 63;
  int wv   = tid >> 6;            // 0..7
  int wm   = wv & 3;              // M strip: o base wm*64
  int wn   = wv >> 2;             // N strip: p base wn*64
  int l15  = lane & 15;
  int kseg = lane >> 4;           // 0..3

  const short* A = (const short*)Ap;
  const short* Yb = (const short*)Yg;

  f32x4 acc[4][4] = {};

  size_t abase = (size_t)(wm * 64 + l15) * KDIM + kseg * 8;
  size_t bbase = ((size_t)bid * 128 + wn * 64 + l15) * KDIM + kseg * 8;

  for (int k0 = 0; k0 < KDIM; k0 += 32) {
    bf16x8 a[4], bfr[4];
#pragma unroll
    for (int m = 0; m < 4; ++m)
      a[m] = *(const bf16x8*)(A + abase + (size_t)m * 16 * KDIM + k0);
#pragma unroll
    for (int n = 0; n < 4; ++n)
      bfr[n] = *(const bf16x8*)(Yb + bbase + (size_t)n * 16 * KDIM + k0);
#pragma unroll
    for (int m = 0; m < 4; ++m)
#pragma unroll
      for (int n = 0; n < 4; ++n)
        acc[m][n] = __builtin_amdgcn_mfma_f32_16x16x32_bf16(a[m], bfr[n],
                                                            acc[m][n], 0, 0, 0);
  }

  // epilogue: C/D layout col = lane&15 (pixel), row = (lane>>4)*4 + r (o)
  int b    = bid >> 7;
  int hrow = bid & 127;
#pragma unroll
  for (int m = 0; m < 4; ++m) {
#pragma unroll
    for (int n = 0; n < 4; ++n) {
#pragma unroll
      for (int r = 0; r < 4; ++r) {
        int o = wm * 64 + m * 16 + kseg * 4 + r;
        int w = wn * 64 + n * 16 + l15;
        out[((size_t)(b * 256 + o) << 14) + (hrow << 7) + w] =
            fmaxf(acc[m][n][r], 0.f);
      }
    }
  }
}

extern "C" void kernel_launch(void* const* d_in, const int* in_sizes, int n_in,
                              void* d_out, int out_size, void* d_ws, size_t ws_size,
                              hipStream_t stream) {
  (void)in_sizes; (void)n_in; (void)out_size; (void)ws_size;
  const float* x     = (const float*)d_in[0];
  const float* wh1   = (const float*)d_in[1];
  const float* wh2   = (const float*)d_in[2];
  const float* wv1   = (const float*)d_in[3];
  const float* wv2   = (const float*)d_in[4];
  const float* wproj = (const float*)d_in[5];
  float* out = (float*)d_out;

  unsigned short* Yg = (unsigned short*)d_ws;                       // 268435456 B
  unsigned short* Ap = (unsigned short*)((char*)d_ws
                        + (size_t)NPIX * KDIM * sizeof(unsigned short)); // +512 KB

  hipLaunchKernelGGL(prep_kernel, dim3(KDIM * CC / 256), dim3(256), 0, stream,
                     wproj, Ap);
  hipLaunchKernelGGL(conv_kernel, dim3(BB * CC * (HH / 16)), dim3(256), 0, stream,
                     x, wh1, wh2, wv1, wv2, Yg);
  hipLaunchKernelGGL(gemm_kernel, dim3(BB * HH), dim3(512), 0, stream,
                     Ap, Yg, out);
}

// Round 2
// 553.821 us; speedup vs baseline: 1.1832x; 1.1832x over previous
//
#include <hip/hip_runtime.h>
#include <hip/hip_bf16.h>

#define BB 8
#define CC 256
#define HH 128
#define WW 128
#define KS 9
#define PADR 4
#define NPIX (BB*HH*WW)   // 131072
#define KDIM (4*CC)       // 1024

typedef __attribute__((ext_vector_type(8))) short bf16x8;
typedef __attribute__((ext_vector_type(4))) float f32x4;

static __device__ __forceinline__ unsigned short f2bf(float f) {
  union { float f; unsigned u; } v; v.f = f;
  unsigned r = v.u + 0x7FFF + ((v.u >> 16) & 1);   // RNE
  return (unsigned short)(r >> 16);
}

// global -> LDS direct copy, 16B per lane
static __device__ __forceinline__ void gload_lds16(const void* g, void* l) {
  __builtin_amdgcn_global_load_lds(
      (const __attribute__((address_space(1))) void*)g,
      (__attribute__((address_space(3))) void*)l, 16, 0, 0);
}

// ---------------------------------------------------------------------------
// Prep: A'[o][k'] bf16, k' = c*4 + t, from wproj[o][t*256 + c] (fp32)
// ---------------------------------------------------------------------------
__global__ void prep_kernel(const float* __restrict__ wproj,
                            unsigned short* __restrict__ Ap) {
  int idx = blockIdx.x * 256 + threadIdx.x;    // 0 .. 262143
  int o  = idx >> 10;
  int kp = idx & 1023;
  int c  = kp >> 2;
  int t  = kp & 3;
  Ap[idx] = f2bf(wproj[o * 1024 + t * 256 + c]);
}

// ---------------------------------------------------------------------------
// K1 v2: depthwise convs -> Y bf16, Y[p][k'], k' = c*4+t.
// Block = one (b,h) row; 256 threads = 256 channels (lanes along c).
// Stores: lane c writes 8B at Y[p][c*4] -> 512B contiguous per wave-store.
// Reads: per-lane 64KB stride, line-efficient, L2/L3-served.
// XCD swizzle: 1024 blocks -> one image per XCD (sliding-row L2 reuse).
// ---------------------------------------------------------------------------
__global__ __launch_bounds__(256)
void conv_kernel(const float* __restrict__ x,
                 const float* __restrict__ wh1, const float* __restrict__ wh2,
                 const float* __restrict__ wv1, const float* __restrict__ wv2,
                 unsigned short* __restrict__ Y) {
  int bid = blockIdx.x;
  bid = (bid & 7) * 128 + (bid >> 3);   // XCD-chunked: image b -> XCD b
  int h = bid & 127;
  int c = threadIdx.x;

  float W1[KS], W2[KS], W3[KS], W4[KS];
#pragma unroll
  for (int k = 0; k < KS; ++k) {
    W1[k] = wh1[c * KS + k];
    W2[k] = wh2[c * KS + k];
    W3[k] = wv1[c * KS + k];
    W4[k] = wv2[c * KS + k];
  }

  int b = bid >> 7;
  const float* xc = x + ((size_t)(b * CC + c)) * (HH * WW);
  unsigned short* yrow = Y + (size_t)bid * 128 * KDIM + (size_t)c * 4;

  for (int w0 = 0; w0 < WW; w0 += 8) {
    // horizontal window x[h][w0-4 .. w0+11]
    float hw[16];
    {
      const float* xr = xc + h * WW;
#pragma unroll
      for (int s = 0; s < 4; ++s) {
        int wb = w0 - 4 + s * 4;
        float4 seg;
        if (wb >= 0 && wb <= WW - 4) seg = *(const float4*)(xr + wb);
        else seg = make_float4(0.f, 0.f, 0.f, 0.f);
        hw[s*4+0]=seg.x; hw[s*4+1]=seg.y; hw[s*4+2]=seg.z; hw[s*4+3]=seg.w;
      }
    }
    // vertical windows rows h-4..h+4, cols [w0, w0+8)
    float vv[KS][8];
#pragma unroll
    for (int k = 0; k < KS; ++k) {
      int r = h + k - PADR;
      if (r >= 0 && r < HH) {
        const float* rp = xc + r * WW + w0;
        float4 a = *(const float4*)(rp);
        float4 b4 = *(const float4*)(rp + 4);
        vv[k][0]=a.x; vv[k][1]=a.y; vv[k][2]=a.z; vv[k][3]=a.w;
        vv[k][4]=b4.x; vv[k][5]=b4.y; vv[k][6]=b4.z; vv[k][7]=b4.w;
      } else {
#pragma unroll
        for (int j = 0; j < 8; ++j) vv[k][j] = 0.f;
      }
    }
#pragma unroll
    for (int w = 0; w < 8; ++w) {
      float s1 = 0.f, s2 = 0.f, s3 = 0.f, s4 = 0.f;
#pragma unroll
      for (int k = 0; k < KS; ++k) {
        float xh = hw[w + k];
        s1 = fmaf(xh, W1[k], s1);
        s2 = fmaf(xh, W2[k], s2);
        float xv = vv[k][w];
        s3 = fmaf(xv, W3[k], s3);
        s4 = fmaf(xv, W4[k], s4);
      }
      unsigned u0 = (unsigned)f2bf(s1) | ((unsigned)f2bf(s2) << 16);
      unsigned u1 = (unsigned)f2bf(s3) | ((unsigned)f2bf(s4) << 16);
      *(uint2*)(yrow + (size_t)(w0 + w) * KDIM) = make_uint2(u0, u1);
    }
  }
}

// ---------------------------------------------------------------------------
// K2 v2: out = relu(A'(256x1024) @ Y^T(1024x131072)), m97 structure.
// 128x128 tile, BK=64, LDS linear, global_load_lds(16B), 2-barrier loop.
// 256 thr = 4 waves (2 om x 2 pn), wave tile 64x64 = 4x4 frags 16x16x32.
// Grid 2048 = 2 o-tiles x 1024 p-tiles, XCD-chunked swizzle.
// ---------------------------------------------------------------------------
__global__ __launch_bounds__(256)
void gemm_kernel(const unsigned short* __restrict__ Ap,
                 const unsigned short* __restrict__ Yg,
                 float* __restrict__ out) {
  __shared__ short As[128 * 64];
  __shared__ short Bs[128 * 64];

  int bid = blockIdx.x;
  bid = (bid & 7) * 256 + (bid >> 3);   // 2048 = 8 XCD x 256
  int otile = bid & 1;
  int pt    = bid >> 1;                 // 0..1023 = b*128 + h
  int tid   = threadIdx.x;
  int lane  = tid & 63;
  int wv    = tid >> 6;
  int om    = wv & 1;
  int pn    = wv >> 1;
  int l15   = lane & 15;
  int kseg  = lane >> 4;

  const short* A  = (const short*)Ap + (size_t)(otile * 128) * KDIM;
  const short* Bg = (const short*)Yg + (size_t)pt * 128 * KDIM;

  int srow = tid >> 3;          // + i*32
  int skc  = (tid & 7) * 8;

  f32x4 acc[4][4] = {};

  for (int k0 = 0; k0 < KDIM; k0 += 64) {
#pragma unroll
    for (int i = 0; i < 4; ++i) {
      int rr = i * 32 + srow;
      gload_lds16(A  + (size_t)rr * KDIM + k0 + skc, &As[rr * 64 + skc]);
      gload_lds16(Bg + (size_t)rr * KDIM + k0 + skc, &Bs[rr * 64 + skc]);
    }
    __syncthreads();
#pragma unroll
    for (int kk = 0; kk < 2; ++kk) {
      bf16x8 af[4], bfr[4];
#pragma unroll
      for (int m = 0; m < 4; ++m)
        af[m] = *(const bf16x8*)&As[(om * 64 + m * 16 + l15) * 64 + kk * 32 + kseg * 8];
#pragma unroll
      for (int n = 0; n < 4; ++n)
        bfr[n] = *(const bf16x8*)&Bs[(pn * 64 + n * 16 + l15) * 64 + kk * 32 + kseg * 8];
#pragma unroll
      for (int m = 0; m < 4; ++m)
#pragma unroll
        for (int n = 0; n < 4; ++n)
          acc[m][n] = __builtin_amdgcn_mfma_f32_16x16x32_bf16(af[m], bfr[n],
                                                              acc[m][n], 0, 0, 0);
    }
    __syncthreads();
  }

  int b = pt >> 7, h = pt & 127;
#pragma unroll
  for (int m = 0; m < 4; ++m) {
#pragma unroll
    for (int n = 0; n < 4; ++n) {
#pragma unroll
      for (int r = 0; r < 4; ++r) {
        int o = otile * 128 + om * 64 + m * 16 + kseg * 4 + r;
        int w = pn * 64 + n * 16 + l15;
        out[((size_t)(b * 256 + o) << 14) + (h << 7) + w] =
            fmaxf(acc[m][n][r], 0.f);
      }
    }
  }
}

extern "C" void kernel_launch(void* const* d_in, const int* in_sizes, int n_in,
                              void* d_out, int out_size, void* d_ws, size_t ws_size,
                              hipStream_t stream) {
  (void)in_sizes; (void)n_in; (void)out_size; (void)ws_size;
  const float* x     = (const float*)d_in[0];
  const float* wh1   = (const float*)d_in[1];
  const float* wh2   = (const float*)d_in[2];
  const float* wv1   = (const float*)d_in[3];
  const float* wv2   = (const float*)d_in[4];
  const float* wproj = (const float*)d_in[5];
  float* out = (float*)d_out;

  unsigned short* Yg = (unsigned short*)d_ws;                       // 268435456 B
  unsigned short* Ap = (unsigned short*)((char*)d_ws
                        + (size_t)NPIX * KDIM * sizeof(unsigned short)); // +512 KB

  hipLaunchKernelGGL(prep_kernel, dim3(KDIM * CC / 256), dim3(256), 0, stream,
                     wproj, Ap);
  hipLaunchKernelGGL(conv_kernel, dim3(BB * HH), dim3(256), 0, stream,
                     x, wh1, wh2, wv1, wv2, Yg);
  hipLaunchKernelGGL(gemm_kernel, dim3(2 * BB * HH), dim3(512 / 2), 0, stream,
                     Ap, Yg, out);
}